// Round 11
// baseline (293.524 us; speedup 1.0000x reference)
//
#include <hip/hip_runtime.h>

#define NN 50000
#define NE 800000
#define D 128
#define NTILE 3128        // 16-row tiles: 3128*16 = 50048
#define GGRID 768         // persistent gemm blocks (3/CU exact)
#define XBLK 6250         // x conversion blocks (NN*D/4/256)
#define WBLK 96           // weight conversion blocks (6 * 16)
#define BBLK 250          // edge-binning blocks
#define EPB 3200          // NE / BBLK edges per binning block
#define NBUCK 196         // dst>>8 buckets (256 nodes each)
#define STAGE_CAP 64      // LDS staging slots/bucket (mean 16.3, +12 sigma)
#define BIN_CAP 4608      // global bin capacity (mean 4096, +8 sigma)
#define SORT_WIN 4608     // LDS sort window entries
#define LDS_STRIDE 136    // tile row stride in ushorts (128 + 8 pad)

typedef __attribute__((ext_vector_type(8))) short bf16x8;
typedef __attribute__((ext_vector_type(4))) float f32x4;

__device__ inline unsigned short f2bf(float f) {
    union { float f; unsigned u; } v; v.f = f;
    unsigned r = v.u + 0x7FFF + ((v.u >> 16) & 1);  // RNE
    return (unsigned short)(r >> 16);
}
__device__ inline float bf2f(unsigned b) {
    union { unsigned u; float f; } v; v.u = b << 16;
    return v.f;
}

// ---- fused: convert x + 6 weights to bf16; bin edges to dst-buckets ----
__global__ __launch_bounds__(256)
void prep(const float* __restrict__ x,
          const float* __restrict__ w0, const float* __restrict__ w1,
          const float* __restrict__ w2, const float* __restrict__ w3,
          const float* __restrict__ w4, const float* __restrict__ w5,
          const int* __restrict__ ei,
          unsigned short* __restrict__ xb, unsigned short* __restrict__ wb,
          unsigned* __restrict__ bin, int* __restrict__ bcur) {
    const unsigned b = blockIdx.x;
    if (b < XBLK) {
        int i = b * 256 + threadIdx.x;
        float4 v = ((const float4*)x)[i];
        ushort4 o = {f2bf(v.x), f2bf(v.y), f2bf(v.z), f2bf(v.w)};
        ((ushort4*)xb)[i] = o;
    } else if (b < XBLK + WBLK) {
        const float* ws_[6] = {w0, w1, w2, w3, w4, w5};
        int wi = (int)(b - XBLK) >> 4;
        int off = ((int)(b - XBLK) & 15) * 256 + threadIdx.x;  // float4 idx
        float4 v = ((const float4*)ws_[wi])[off];
        ushort4 o = {f2bf(v.x), f2bf(v.y), f2bf(v.z), f2bf(v.w)};
        ((ushort4*)(wb + wi * D * D))[off] = o;
    } else {
        // bin 3200 edges: LDS-staged per-bucket appends, contiguous global spans.
        __shared__ unsigned stage[NBUCK * STAGE_CAP];
        __shared__ int bcnt[NBUCK];
        __shared__ int sbase[NBUCK];
        const int ebase = (int)(b - XBLK - WBLK) * EPB;
        if (threadIdx.x < NBUCK) bcnt[threadIdx.x] = 0;
        __syncthreads();
        for (int j = threadIdx.x; j < EPB; j += 256) {
            const int e = ebase + j;
            const int dst = ei[NE + e];
            const int src = ei[e];
            const int bk = dst >> 8;
            const unsigned u = (unsigned)src | ((unsigned)(dst & 255) << 16);
            const int slot = atomicAdd(&bcnt[bk], 1);
            if (slot < STAGE_CAP) {
                stage[bk * STAGE_CAP + slot] = u;
            } else {  // statistically-never overflow: direct append
                const int gp = atomicAdd(&bcur[bk], 1);
                if (gp < BIN_CAP) bin[bk * BIN_CAP + gp] = u;
            }
        }
        __syncthreads();
        if (threadIdx.x < NBUCK) {
            int c = bcnt[threadIdx.x];
            if (c > STAGE_CAP) c = STAGE_CAP;
            sbase[threadIdx.x] = atomicAdd(&bcur[threadIdx.x], c);
        }
        __syncthreads();
        const int wv = threadIdx.x >> 6, ln = threadIdx.x & 63;
        for (int bk = wv; bk < NBUCK; bk += 4) {
            int c = bcnt[bk];
            if (c > STAGE_CAP) c = STAGE_CAP;
            if (ln < c) {
                int p = sbase[bk] + ln;
                if (p < BIN_CAP) bin[bk * BIN_CAP + p] = stage[bk * STAGE_CAP + ln];
            }
        }
    }
}

// ---- exclusive scan of 196 bucket counts -> bbase[0..196]; row_start[NN]=NE ----
__global__ __launch_bounds__(256)
void bucket_scan(const int* __restrict__ bcur, int* __restrict__ bbase,
                 int* __restrict__ row_start) {
    __shared__ int tmp[256];
    int v = (threadIdx.x < NBUCK) ? bcur[threadIdx.x] : 0;
    tmp[threadIdx.x] = v;
    __syncthreads();
    for (int off = 1; off < 256; off <<= 1) {
        int t = (threadIdx.x >= (unsigned)off) ? tmp[threadIdx.x - off] : 0;
        __syncthreads();
        tmp[threadIdx.x] += t;
        __syncthreads();
    }
    if (threadIdx.x <= NBUCK)
        bbase[threadIdx.x] = (threadIdx.x == 0) ? 0 : tmp[threadIdx.x - 1];
    if (threadIdx.x == 0) row_start[NN] = NE;
}

// ---- persistent gemm body: out = relu(A@W.T + bias), bf16 out ----
__device__ inline void gemm_body(const unsigned short* __restrict__ A,
                                 const unsigned short* __restrict__ W,
                                 const float* __restrict__ bias,
                                 unsigned short* __restrict__ out,
                                 int bid, int nblk) {
    const int lane = threadIdx.x & 63;
    const int wave = threadIdx.x >> 6;
    const int quad = lane >> 4;
    const int l16 = lane & 15;
    const int c0 = wave * 32 + l16;
    const int c1 = c0 + 16;

    const float bv0 = bias[c0];
    const float bv1 = bias[c1];

    bf16x8 w10[4], w11[4];
#pragma unroll
    for (int kt = 0; kt < 4; ++kt) {
        const int ko = kt * 32 + quad * 8;
        w10[kt] = *(const bf16x8*)&W[c0 * D + ko];
        w11[kt] = *(const bf16x8*)&W[c1 * D + ko];
    }

    for (int t = bid; t < NTILE; t += nblk) {
        const int row0 = t * 16;
        int r = row0 + l16;
        const int arow = (r < NN ? r : NN - 1) * D;

        f32x4 acc0 = (f32x4){0.f, 0.f, 0.f, 0.f};
        f32x4 acc1 = (f32x4){0.f, 0.f, 0.f, 0.f};
#pragma unroll
        for (int kt = 0; kt < 4; ++kt) {
            const int ko = kt * 32 + quad * 8;
            bf16x8 a1 = *(const bf16x8*)&A[arow + ko];
            acc0 = __builtin_amdgcn_mfma_f32_16x16x32_bf16(a1, w10[kt], acc0, 0, 0, 0);
            acc1 = __builtin_amdgcn_mfma_f32_16x16x32_bf16(a1, w11[kt], acc1, 0, 0, 0);
        }

#pragma unroll
        for (int rr = 0; rr < 4; ++rr) {
            const int row = row0 + quad * 4 + rr;
            if (row < NN) {
                float v0 = acc0[rr] + bv0;
                float v1 = acc1[rr] + bv1;
                v0 = v0 > 0.f ? v0 : 0.f;
                v1 = v1 > 0.f ? v1 : 0.f;
                out[row * D + c0] = f2bf(v0);
                out[row * D + c1] = f2bf(v1);
            }
        }
    }
}

// ---- fused: persistent gemm (blocks [0,GGRID)) + bucket CSR sort ----
__global__ __launch_bounds__(256)
void gemm_fill(const unsigned short* __restrict__ A,
               const unsigned short* __restrict__ W,
               const float* __restrict__ bias, unsigned short* __restrict__ outp,
               const int* __restrict__ bbase, const unsigned* __restrict__ bin,
               int* __restrict__ row_start, unsigned short* __restrict__ src16) {
    if (blockIdx.x < GGRID) {
        gemm_body(A, W, bias, outp, blockIdx.x, GGRID);
        return;
    }
    __shared__ int hist[256];
    __shared__ unsigned short win[SORT_WIN];
    const int b = (int)blockIdx.x - GGRID;  // 0..NBUCK-1
    const int nbase = b << 8;
    const int nn = (NN - nbase < 256) ? (NN - nbase) : 256;
    const int gb = bbase[b];
    const int span = bbase[b + 1] - gb;
    const unsigned* mybin = bin + (size_t)b * BIN_CAP;

    hist[threadIdx.x] = 0;
    __syncthreads();
    for (int i = threadIdx.x; i < span; i += 256)
        atomicAdd(&hist[mybin[i] >> 16], 1);
    __syncthreads();

    const int hv = hist[threadIdx.x];
    __syncthreads();
    hist[threadIdx.x] = hv;
    __syncthreads();
    for (int off = 1; off < 256; off <<= 1) {
        int tv = (threadIdx.x >= (unsigned)off) ? hist[threadIdx.x - off] : 0;
        __syncthreads();
        hist[threadIdx.x] += tv;
        __syncthreads();
    }
    const int ex = hist[threadIdx.x] - hv;
    __syncthreads();
    hist[threadIdx.x] = ex;
    if ((int)threadIdx.x < nn) row_start[nbase + threadIdx.x] = gb + ex;
    __syncthreads();

    for (int i = threadIdx.x; i < span; i += 256) {
        const unsigned u = mybin[i];
        const int pos = atomicAdd(&hist[u >> 16], 1);
        const unsigned short sv = (unsigned short)(u & 0xffffu);
        if (pos < SORT_WIN) win[pos] = sv;
        else src16[gb + pos] = sv;  // statistical overflow fallback
    }
    __syncthreads();
    const int lim = span < SORT_WIN ? span : SORT_WIN;
    for (int i = threadIdx.x; i < lim; i += 256) src16[gb + i] = win[i];
}

// ---- gather a 16-node mean tile into LDS (4 waves x 4 nodes) ----
__device__ inline void acc8(float* s, uint4 r) {
    s[0] += bf2f(r.x & 0xffffu); s[1] += bf2f(r.x >> 16);
    s[2] += bf2f(r.y & 0xffffu); s[3] += bf2f(r.y >> 16);
    s[4] += bf2f(r.z & 0xffffu); s[5] += bf2f(r.z >> 16);
    s[6] += bf2f(r.w & 0xffffu); s[7] += bf2f(r.w >> 16);
}

__device__ inline void gather_tile(const uint4* __restrict__ P4,
                                   const int* __restrict__ row_start,
                                   const unsigned short* __restrict__ src16,
                                   int row0, unsigned short* tile) {
    const int lane = threadIdx.x & 63;
    const int wave = threadIdx.x >> 6;
    const int q = lane >> 4;
    const int l16 = lane & 15;
#pragma unroll
    for (int j = 0; j < 4; ++j) {
        const int rl = wave * 4 + j;
        const int n = row0 + rl;
        int b = 0, e = 0;
        if (n < NN) { b = row_start[n]; e = row_start[n + 1]; }

        float s[8];
#pragma unroll
        for (int k = 0; k < 8; ++k) s[k] = 0.f;

        int i = b;
        for (; i + 32 <= e; i += 32) {
            int idx[8];
            uint4 r[8];
#pragma unroll
            for (int k = 0; k < 8; ++k) idx[k] = src16[i + k * 4 + q];
#pragma unroll
            for (int k = 0; k < 8; ++k) r[k] = P4[idx[k] * 16 + l16];
#pragma unroll
            for (int k = 0; k < 8; ++k) acc8(s, r[k]);
        }
        for (; i + 16 <= e; i += 16) {
            int i0 = src16[i + 0 + q], i1 = src16[i + 4 + q];
            int i2 = src16[i + 8 + q], i3 = src16[i + 12 + q];
            uint4 r0 = P4[i0 * 16 + l16];
            uint4 r1 = P4[i1 * 16 + l16];
            uint4 r2 = P4[i2 * 16 + l16];
            uint4 r3 = P4[i3 * 16 + l16];
            acc8(s, r0); acc8(s, r1); acc8(s, r2); acc8(s, r3);
        }
        for (; i + 4 <= e; i += 4) {
            int i0 = src16[i + q];
            uint4 r0 = P4[i0 * 16 + l16];
            acc8(s, r0);
        }
        const int rem = e - i;
        if (q < rem) {
            int i0 = src16[i + q];
            uint4 r0 = P4[i0 * 16 + l16];
            acc8(s, r0);
        }

#pragma unroll
        for (int k = 0; k < 8; ++k) {
            s[k] += __shfl_xor(s[k], 16);
            s[k] += __shfl_xor(s[k], 32);
        }

        const int deg = e - b;
        const float inv = 1.0f / (float)(deg > 0 ? deg : 1);
        if (q == 0) {
            uint4 o;
            o.x = (unsigned)f2bf(s[0] * inv) | ((unsigned)f2bf(s[1] * inv) << 16);
            o.y = (unsigned)f2bf(s[2] * inv) | ((unsigned)f2bf(s[3] * inv) << 16);
            o.z = (unsigned)f2bf(s[4] * inv) | ((unsigned)f2bf(s[5] * inv) << 16);
            o.w = (unsigned)f2bf(s[6] * inv) | ((unsigned)f2bf(s[7] * inv) << 16);
            *(uint4*)&tile[rl * LDS_STRIDE + l16 * 8] = o;
        }
    }
}

// ---- fused layer-1: gather-mean + dual combine + layer-2 projection ----
// Per 16-node tile: agg -> LDS; h = relu(agg@Wl.T + x@Wr.T + bl) -> bufH &
// LDS; p2 = relu(h@Wp.T + bp) -> bufP2. One block per tile, 3128 blocks.
__global__ __launch_bounds__(256, 4)
void gather_combine_proj(const uint4* __restrict__ P4,
                         const int* __restrict__ row_start,
                         const unsigned short* __restrict__ src16,
                         const unsigned short* __restrict__ Wl,
                         const unsigned short* __restrict__ X,
                         const unsigned short* __restrict__ Wr,
                         const float* __restrict__ bl,
                         unsigned short* __restrict__ bufH,
                         const unsigned short* __restrict__ Wp,
                         const float* __restrict__ bp,
                         unsigned short* __restrict__ bufP2) {
    __shared__ __align__(16) unsigned short tile[16 * LDS_STRIDE];
    const int lane = threadIdx.x & 63;
    const int wave = threadIdx.x >> 6;
    const int quad = lane >> 4;
    const int l16 = lane & 15;
    const int row0 = blockIdx.x * 16;

    gather_tile(P4, row_start, src16, row0, tile);
    __syncthreads();

    const int c0 = wave * 32 + l16;
    const int c1 = c0 + 16;
    int r = row0 + l16;
    const int arow = (r < NN ? r : NN - 1) * D;

    // phase A: dual combine (A1 from LDS agg tile, A2 from global X)
    f32x4 acc0 = (f32x4){0.f, 0.f, 0.f, 0.f};
    f32x4 acc1 = (f32x4){0.f, 0.f, 0.f, 0.f};
#pragma unroll
    for (int kt = 0; kt < 4; ++kt) {
        const int ko = kt * 32 + quad * 8;
        bf16x8 aL = *(const bf16x8*)&tile[l16 * LDS_STRIDE + ko];
        bf16x8 aX = *(const bf16x8*)&X[arow + ko];
        bf16x8 bl0 = *(const bf16x8*)&Wl[c0 * D + ko];
        bf16x8 bl1 = *(const bf16x8*)&Wl[c1 * D + ko];
        bf16x8 br0 = *(const bf16x8*)&Wr[c0 * D + ko];
        bf16x8 br1 = *(const bf16x8*)&Wr[c1 * D + ko];
        acc0 = __builtin_amdgcn_mfma_f32_16x16x32_bf16(aL, bl0, acc0, 0, 0, 0);
        acc1 = __builtin_amdgcn_mfma_f32_16x16x32_bf16(aL, bl1, acc1, 0, 0, 0);
        acc0 = __builtin_amdgcn_mfma_f32_16x16x32_bf16(aX, br0, acc0, 0, 0, 0);
        acc1 = __builtin_amdgcn_mfma_f32_16x16x32_bf16(aX, br1, acc1, 0, 0, 0);
    }
    __syncthreads();  // all agg-tile reads done before overwrite

    const float b0 = bl[c0], b1 = bl[c1];
#pragma unroll
    for (int rr = 0; rr < 4; ++rr) {
        const int row = row0 + quad * 4 + rr;
        float v0 = acc0[rr] + b0;
        float v1 = acc1[rr] + b1;
        v0 = v0 > 0.f ? v0 : 0.f;
        v1 = v1 > 0.f ? v1 : 0.f;
        const unsigned short h0 = f2bf(v0), h1 = f2bf(v1);
        tile[(quad * 4 + rr) * LDS_STRIDE + c0] = h0;
        tile[(quad * 4 + rr) * LDS_STRIDE + c1] = h1;
        if (row < NN) {
            bufH[row * D + c0] = h0;
            bufH[row * D + c1] = h1;
        }
    }
    __syncthreads();

    // phase B: layer-2 projection of the combined tile
    f32x4 p0 = (f32x4){0.f, 0.f, 0.f, 0.f};
    f32x4 p1 = (f32x4){0.f, 0.f, 0.f, 0.f};
#pragma unroll
    for (int kt = 0; kt < 4; ++kt) {
        const int ko = kt * 32 + quad * 8;
        bf16x8 aL = *(const bf16x8*)&tile[l16 * LDS_STRIDE + ko];
        bf16x8 wp0 = *(const bf16x8*)&Wp[c0 * D + ko];
        bf16x8 wp1 = *(const bf16x8*)&Wp[c1 * D + ko];
        p0 = __builtin_amdgcn_mfma_f32_16x16x32_bf16(aL, wp0, p0, 0, 0, 0);
        p1 = __builtin_amdgcn_mfma_f32_16x16x32_bf16(aL, wp1, p1, 0, 0, 0);
    }
    const float q0 = bp[c0], q1 = bp[c1];
#pragma unroll
    for (int rr = 0; rr < 4; ++rr) {
        const int row = row0 + quad * 4 + rr;
        if (row < NN) {
            float v0 = p0[rr] + q0;
            float v1 = p1[rr] + q1;
            v0 = v0 > 0.f ? v0 : 0.f;
            v1 = v1 > 0.f ? v1 : 0.f;
            bufP2[row * D + c0] = f2bf(v0);
            bufP2[row * D + c1] = f2bf(v1);
        }
    }
}

// ---- fused layer-2: gather-mean + dual combine -> f32 out ----
__global__ __launch_bounds__(256, 4)
void gather_combine_out(const uint4* __restrict__ P4,
                        const int* __restrict__ row_start,
                        const unsigned short* __restrict__ src16,
                        const unsigned short* __restrict__ Wl,
                        const unsigned short* __restrict__ H,
                        const unsigned short* __restrict__ Wr,
                        const float* __restrict__ bl,
                        float* __restrict__ out) {
    __shared__ __align__(16) unsigned short tile[16 * LDS_STRIDE];
    const int lane = threadIdx.x & 63;
    const int wave = threadIdx.x >> 6;
    const int quad = lane >> 4;
    const int l16 = lane & 15;
    const int row0 = blockIdx.x * 16;

    gather_tile(P4, row_start, src16, row0, tile);
    __syncthreads();

    const int c0 = wave * 32 + l16;
    const int c1 = c0 + 16;
    int r = row0 + l16;
    const int arow = (r < NN ? r : NN - 1) * D;

    f32x4 acc0 = (f32x4){0.f, 0.f, 0.f, 0.f};
    f32x4 acc1 = (f32x4){0.f, 0.f, 0.f, 0.f};
#pragma unroll
    for (int kt = 0; kt < 4; ++kt) {
        const int ko = kt * 32 + quad * 8;
        bf16x8 aL = *(const bf16x8*)&tile[l16 * LDS_STRIDE + ko];
        bf16x8 aH = *(const bf16x8*)&H[arow + ko];
        bf16x8 bl0 = *(const bf16x8*)&Wl[c0 * D + ko];
        bf16x8 bl1 = *(const bf16x8*)&Wl[c1 * D + ko];
        bf16x8 br0 = *(const bf16x8*)&Wr[c0 * D + ko];
        bf16x8 br1 = *(const bf16x8*)&Wr[c1 * D + ko];
        acc0 = __builtin_amdgcn_mfma_f32_16x16x32_bf16(aL, bl0, acc0, 0, 0, 0);
        acc1 = __builtin_amdgcn_mfma_f32_16x16x32_bf16(aL, bl1, acc1, 0, 0, 0);
        acc0 = __builtin_amdgcn_mfma_f32_16x16x32_bf16(aH, br0, acc0, 0, 0, 0);
        acc1 = __builtin_amdgcn_mfma_f32_16x16x32_bf16(aH, br1, acc1, 0, 0, 0);
    }

    const float b0 = bl[c0], b1 = bl[c1];
#pragma unroll
    for (int rr = 0; rr < 4; ++rr) {
        const int row = row0 + quad * 4 + rr;
        if (row < NN) {
            out[row * D + c0] = acc0[rr] + b0;
            out[row * D + c1] = acc1[rr] + b1;
        }
    }
}

extern "C" void kernel_launch(void* const* d_in, const int* in_sizes, int n_in,
                              void* d_out, int out_size, void* d_ws, size_t ws_size,
                              hipStream_t stream) {
    const float* x   = (const float*)d_in[0];
    const int*   ei  = (const int*)d_in[1];
    const float* Wp1 = (const float*)d_in[2];
    const float* bp1 = (const float*)d_in[3];
    const float* Wl1 = (const float*)d_in[4];
    const float* bl1 = (const float*)d_in[5];
    const float* Wr1 = (const float*)d_in[6];
    const float* Wp2 = (const float*)d_in[7];
    const float* bp2 = (const float*)d_in[8];
    const float* Wl2 = (const float*)d_in[9];
    const float* bl2 = (const float*)d_in[10];
    const float* Wr2 = (const float*)d_in[11];
    float* out = (float*)d_out;

    char* ws = (char*)d_ws;
    size_t off = 0;
    auto alloc = [&](size_t bytes) {
        void* p = ws + off;
        off += (bytes + 511) & ~511ull;
        return p;
    };
    unsigned short* Wb   = (unsigned short*)alloc((size_t)6 * D * D * 2);
    unsigned short* xb   = (unsigned short*)alloc((size_t)NN * D * 2);
    unsigned short* bufP = (unsigned short*)alloc((size_t)NN * D * 2);  // proj-1
    unsigned short* bufP2= (unsigned short*)alloc((size_t)NN * D * 2);  // proj-2
    unsigned short* bufH = (unsigned short*)alloc((size_t)NN * D * 2);  // layer-1 out
    int* row_start  = (int*)alloc((size_t)(NN + 1) * 4);
    int* bcur       = (int*)alloc((size_t)NBUCK * 4);
    int* bbase      = (int*)alloc((size_t)(NBUCK + 1) * 4);
    unsigned* bin   = (unsigned*)alloc((size_t)NBUCK * BIN_CAP * 4);
    unsigned short* src16 = (unsigned short*)alloc((size_t)NE * 2);

    // 1. conversions + edge binning (one dispatch)
    hipMemsetAsync(bcur, 0, (size_t)NBUCK * 4, stream);
    prep<<<XBLK + WBLK + BBLK, 256, 0, stream>>>(
        x, Wp1, Wl1, Wr1, Wp2, Wl2, Wr2, ei, xb, Wb, bin, bcur);

    // 2. bucket-count scan (tiny)
    bucket_scan<<<1, 256, 0, stream>>>(bcur, bbase, row_start);

    // 3. layer-1 projection gemm fused with bucket CSR sort (writes row_start)
    gemm_fill<<<GGRID + NBUCK, 256, 0, stream>>>(
        xb, Wb + 0 * D * D, bp1, bufP, bbase, bin, row_start, src16);

    // 4. layer-1 gather+combine fused with layer-2 projection
    gather_combine_proj<<<NTILE, 256, 0, stream>>>(
        (const uint4*)bufP, row_start, src16,
        Wb + 1 * D * D, xb, Wb + 2 * D * D, bl1, bufH,
        Wb + 3 * D * D, bp2, bufP2);

    // 5. layer-2 gather+combine -> f32 out
    gather_combine_out<<<NTILE, 256, 0, stream>>>(
        (const uint4*)bufP2, row_start, src16,
        Wb + 4 * D * D, bufH, Wb + 5 * D * D, bl2, out);
}

// Round 13
// 263.085 us; speedup vs baseline: 1.1157x; 1.1157x over previous
//
#include <hip/hip_runtime.h>

#define NN 50000
#define NE 800000
#define D 128
#define NTILE 3128        // 16-row tiles: 3128*16 = 50048
#define GGRID 1536        // persistent gemm blocks (6/CU offered)
#define XBLK 6250         // x conversion blocks (NN*D/4/256)
#define WBLK 96           // weight conversion blocks (6 * 16)
#define BBLK 250          // edge-binning blocks
#define EPB 3200          // NE / BBLK edges per binning block
#define NBUCK 196         // dst>>8 buckets (256 nodes each)
#define STAGE_CAP 64      // LDS staging slots/bucket (mean 16.3, +12 sigma)
#define BIN_CAP 4608      // global bin capacity (mean 4096, +8 sigma)
#define SORT_WIN 4608     // LDS sort window entries
#define LDS_STRIDE 136    // tile row stride in ushorts (128 + 8 pad)

typedef __attribute__((ext_vector_type(8))) short bf16x8;
typedef __attribute__((ext_vector_type(4))) float f32x4;

__device__ inline unsigned short f2bf(float f) {
    union { float f; unsigned u; } v; v.f = f;
    unsigned r = v.u + 0x7FFF + ((v.u >> 16) & 1);  // RNE
    return (unsigned short)(r >> 16);
}
__device__ inline float bf2f(unsigned b) {
    union { unsigned u; float f; } v; v.u = b << 16;
    return v.f;
}

// ---- fused: convert x + 6 weights to bf16; bin edges to dst-buckets ----
__global__ __launch_bounds__(256)
void prep(const float* __restrict__ x,
          const float* __restrict__ w0, const float* __restrict__ w1,
          const float* __restrict__ w2, const float* __restrict__ w3,
          const float* __restrict__ w4, const float* __restrict__ w5,
          const int* __restrict__ ei,
          unsigned short* __restrict__ xb, unsigned short* __restrict__ wb,
          unsigned* __restrict__ bin, int* __restrict__ bcur) {
    const unsigned b = blockIdx.x;
    if (b < XBLK) {
        int i = b * 256 + threadIdx.x;
        float4 v = ((const float4*)x)[i];
        ushort4 o = {f2bf(v.x), f2bf(v.y), f2bf(v.z), f2bf(v.w)};
        ((ushort4*)xb)[i] = o;
    } else if (b < XBLK + WBLK) {
        const float* ws_[6] = {w0, w1, w2, w3, w4, w5};
        int wi = (int)(b - XBLK) >> 4;
        int off = ((int)(b - XBLK) & 15) * 256 + threadIdx.x;  // float4 idx
        float4 v = ((const float4*)ws_[wi])[off];
        ushort4 o = {f2bf(v.x), f2bf(v.y), f2bf(v.z), f2bf(v.w)};
        ((ushort4*)(wb + wi * D * D))[off] = o;
    } else {
        // bin 3200 edges: LDS-staged per-bucket appends, contiguous global spans.
        __shared__ unsigned stage[NBUCK * STAGE_CAP];
        __shared__ int bcnt[NBUCK];
        __shared__ int sbase[NBUCK];
        const int ebase = (int)(b - XBLK - WBLK) * EPB;
        if (threadIdx.x < NBUCK) bcnt[threadIdx.x] = 0;
        __syncthreads();
        for (int j = threadIdx.x; j < EPB; j += 256) {
            const int e = ebase + j;
            const int dst = ei[NE + e];
            const int src = ei[e];
            const int bk = dst >> 8;
            const unsigned u = (unsigned)src | ((unsigned)(dst & 255) << 16);
            const int slot = atomicAdd(&bcnt[bk], 1);
            if (slot < STAGE_CAP) {
                stage[bk * STAGE_CAP + slot] = u;
            } else {  // statistically-never overflow: direct append
                const int gp = atomicAdd(&bcur[bk], 1);
                if (gp < BIN_CAP) bin[bk * BIN_CAP + gp] = u;
            }
        }
        __syncthreads();
        if (threadIdx.x < NBUCK) {
            int c = bcnt[threadIdx.x];
            if (c > STAGE_CAP) c = STAGE_CAP;
            sbase[threadIdx.x] = atomicAdd(&bcur[threadIdx.x], c);
        }
        __syncthreads();
        const int wv = threadIdx.x >> 6, ln = threadIdx.x & 63;
        for (int bk = wv; bk < NBUCK; bk += 4) {
            int c = bcnt[bk];
            if (c > STAGE_CAP) c = STAGE_CAP;
            if (ln < c) {
                int p = sbase[bk] + ln;
                if (p < BIN_CAP) bin[bk * BIN_CAP + p] = stage[bk * STAGE_CAP + ln];
            }
        }
    }
}

// ---- persistent gemm body: out = A1@W1.T (+ A2@W2.T) + bias, opt relu ----
template <typename OUTT, bool DUAL>
__device__ inline void gemm_body(const unsigned short* __restrict__ A1,
                                 const unsigned short* __restrict__ W1,
                                 const unsigned short* __restrict__ A2,
                                 const unsigned short* __restrict__ W2,
                                 const float* __restrict__ bias,
                                 OUTT* __restrict__ out, int do_relu,
                                 int bid, int nblk) {
    const int lane = threadIdx.x & 63;
    const int wave = threadIdx.x >> 6;
    const int quad = lane >> 4;
    const int l16 = lane & 15;
    const int c0 = wave * 32 + l16;
    const int c1 = c0 + 16;

    const float bv0 = bias[c0];
    const float bv1 = bias[c1];

    bf16x8 w10[4], w11[4], w20[4], w21[4];
#pragma unroll
    for (int kt = 0; kt < 4; ++kt) {
        const int ko = kt * 32 + quad * 8;
        w10[kt] = *(const bf16x8*)&W1[c0 * D + ko];
        w11[kt] = *(const bf16x8*)&W1[c1 * D + ko];
        if (DUAL) {
            w20[kt] = *(const bf16x8*)&W2[c0 * D + ko];
            w21[kt] = *(const bf16x8*)&W2[c1 * D + ko];
        }
    }

    for (int t = bid; t < NTILE; t += nblk) {
        const int row0 = t * 16;
        int r = row0 + l16;
        const int arow = (r < NN ? r : NN - 1) * D;

        f32x4 acc0 = (f32x4){0.f, 0.f, 0.f, 0.f};
        f32x4 acc1 = (f32x4){0.f, 0.f, 0.f, 0.f};
#pragma unroll
        for (int kt = 0; kt < 4; ++kt) {
            const int ko = kt * 32 + quad * 8;
            bf16x8 a1 = *(const bf16x8*)&A1[arow + ko];
            acc0 = __builtin_amdgcn_mfma_f32_16x16x32_bf16(a1, w10[kt], acc0, 0, 0, 0);
            acc1 = __builtin_amdgcn_mfma_f32_16x16x32_bf16(a1, w11[kt], acc1, 0, 0, 0);
            if (DUAL) {
                bf16x8 a2 = *(const bf16x8*)&A2[arow + ko];
                acc0 = __builtin_amdgcn_mfma_f32_16x16x32_bf16(a2, w20[kt], acc0, 0, 0, 0);
                acc1 = __builtin_amdgcn_mfma_f32_16x16x32_bf16(a2, w21[kt], acc1, 0, 0, 0);
            }
        }

#pragma unroll
        for (int rr = 0; rr < 4; ++rr) {
            const int row = row0 + quad * 4 + rr;
            if (row < NN) {
                float v0 = acc0[rr] + bv0;
                float v1 = acc1[rr] + bv1;
                if (do_relu) {
                    v0 = v0 > 0.f ? v0 : 0.f;
                    v1 = v1 > 0.f ? v1 : 0.f;
                }
                if constexpr (sizeof(OUTT) == 2) {
                    out[row * D + c0] = (OUTT)f2bf(v0);
                    out[row * D + c1] = (OUTT)f2bf(v1);
                } else {
                    out[row * D + c0] = (OUTT)v0;
                    out[row * D + c1] = (OUTT)v1;
                }
            }
        }
    }
}

template <typename OUTT, bool DUAL>
__global__ __launch_bounds__(256)
void gemm_persist(const unsigned short* __restrict__ A1,
                  const unsigned short* __restrict__ W1,
                  const unsigned short* __restrict__ A2,
                  const unsigned short* __restrict__ W2,
                  const float* __restrict__ bias, OUTT* __restrict__ out,
                  int do_relu) {
    gemm_body<OUTT, DUAL>(A1, W1, A2, W2, bias, out, do_relu, blockIdx.x, GGRID);
}

// ---- fused: combine layer-1 + projection layer-2 (persistent tiles) ----
__global__ __launch_bounds__(256)
void combine_proj(const unsigned short* __restrict__ Ag,
                  const unsigned short* __restrict__ Wl,
                  const unsigned short* __restrict__ X,
                  const unsigned short* __restrict__ Wr,
                  const float* __restrict__ bl, unsigned short* __restrict__ bufH,
                  const unsigned short* __restrict__ Wp,
                  const float* __restrict__ bp, unsigned short* __restrict__ bufP2) {
    __shared__ unsigned short tile[16 * LDS_STRIDE];
    const int lane = threadIdx.x & 63;
    const int wave = threadIdx.x >> 6;
    const int quad = lane >> 4;
    const int l16 = lane & 15;
    const int c0 = wave * 32 + l16;
    const int c1 = c0 + 16;

    const float bl0 = bl[c0], bl1 = bl[c1];
    const float bp0 = bp[c0], bp1 = bp[c1];

    bf16x8 wl0[4], wl1[4], wr0[4], wr1[4];
#pragma unroll
    for (int kt = 0; kt < 4; ++kt) {
        const int ko = kt * 32 + quad * 8;
        wl0[kt] = *(const bf16x8*)&Wl[c0 * D + ko];
        wl1[kt] = *(const bf16x8*)&Wl[c1 * D + ko];
        wr0[kt] = *(const bf16x8*)&Wr[c0 * D + ko];
        wr1[kt] = *(const bf16x8*)&Wr[c1 * D + ko];
    }

    for (int t = blockIdx.x; t < NTILE; t += GGRID) {
        const int row0 = t * 16;
        int r = row0 + l16;
        const int arow = (r < NN ? r : NN - 1) * D;

        // phase A: dual combine
        f32x4 acc0 = (f32x4){0.f, 0.f, 0.f, 0.f};
        f32x4 acc1 = (f32x4){0.f, 0.f, 0.f, 0.f};
#pragma unroll
        for (int kt = 0; kt < 4; ++kt) {
            const int ko = kt * 32 + quad * 8;
            bf16x8 a1 = *(const bf16x8*)&Ag[arow + ko];
            bf16x8 a2 = *(const bf16x8*)&X[arow + ko];
            acc0 = __builtin_amdgcn_mfma_f32_16x16x32_bf16(a1, wl0[kt], acc0, 0, 0, 0);
            acc1 = __builtin_amdgcn_mfma_f32_16x16x32_bf16(a1, wl1[kt], acc1, 0, 0, 0);
            acc0 = __builtin_amdgcn_mfma_f32_16x16x32_bf16(a2, wr0[kt], acc0, 0, 0, 0);
            acc1 = __builtin_amdgcn_mfma_f32_16x16x32_bf16(a2, wr1[kt], acc1, 0, 0, 0);
        }
#pragma unroll
        for (int rr = 0; rr < 4; ++rr) {
            const int row = row0 + quad * 4 + rr;
            float v0 = acc0[rr] + bl0;
            float v1 = acc1[rr] + bl1;
            v0 = v0 > 0.f ? v0 : 0.f;
            v1 = v1 > 0.f ? v1 : 0.f;
            const unsigned short h0 = f2bf(v0), h1 = f2bf(v1);
            tile[(quad * 4 + rr) * LDS_STRIDE + c0] = h0;
            tile[(quad * 4 + rr) * LDS_STRIDE + c1] = h1;
            if (row < NN) {
                bufH[row * D + c0] = h0;
                bufH[row * D + c1] = h1;
            }
        }
        __syncthreads();

        // phase B: projection of the tile (A from LDS, Wp from L1/L2)
        f32x4 p0 = (f32x4){0.f, 0.f, 0.f, 0.f};
        f32x4 p1 = (f32x4){0.f, 0.f, 0.f, 0.f};
#pragma unroll
        for (int kt = 0; kt < 4; ++kt) {
            const int ko = kt * 32 + quad * 8;
            bf16x8 aL = *(const bf16x8*)&tile[l16 * LDS_STRIDE + ko];
            bf16x8 wp0 = *(const bf16x8*)&Wp[c0 * D + ko];
            bf16x8 wp1 = *(const bf16x8*)&Wp[c1 * D + ko];
            p0 = __builtin_amdgcn_mfma_f32_16x16x32_bf16(aL, wp0, p0, 0, 0, 0);
            p1 = __builtin_amdgcn_mfma_f32_16x16x32_bf16(aL, wp1, p1, 0, 0, 0);
        }
#pragma unroll
        for (int rr = 0; rr < 4; ++rr) {
            const int row = row0 + quad * 4 + rr;
            if (row < NN) {
                float v0 = p0[rr] + bp0;
                float v1 = p1[rr] + bp1;
                v0 = v0 > 0.f ? v0 : 0.f;
                v1 = v1 > 0.f ? v1 : 0.f;
                bufP2[row * D + c0] = f2bf(v0);
                bufP2[row * D + c1] = f2bf(v1);
            }
        }
        __syncthreads();  // protect LDS tile before next iteration
    }
}

// ---- fused: bucket CSR sort (blocks [0,NBUCK)) + persistent gemm ----
// Sort blocks go FIRST in the grid (critical path for the gathers). Each
// sort block self-computes its global base via an LDS scan of bcur[] —
// no separate bucket_scan dispatch.
__global__ __launch_bounds__(256)
void gemm_fill(const unsigned short* __restrict__ A,
               const unsigned short* __restrict__ W,
               const float* __restrict__ bias, unsigned short* __restrict__ outp,
               const int* __restrict__ bcur, const unsigned* __restrict__ bin,
               int* __restrict__ row_start, unsigned short* __restrict__ src16) {
    if (blockIdx.x >= NBUCK) {
        gemm_body<unsigned short, false>(A, W, nullptr, nullptr, bias, outp, 1,
                                         (int)blockIdx.x - NBUCK, GGRID);
        return;
    }
    __shared__ int hist[256];
    __shared__ int pref[256];
    __shared__ unsigned short win[SORT_WIN];
    const int b = (int)blockIdx.x;  // 0..NBUCK-1
    const int nbase = b << 8;
    const int nn = (NN - nbase < 256) ? (NN - nbase) : 256;

    // self-scan of bucket counts -> gb (exclusive prefix), span
    int v = (threadIdx.x < NBUCK) ? bcur[threadIdx.x] : 0;
    pref[threadIdx.x] = v;
    __syncthreads();
    for (int off = 1; off < 256; off <<= 1) {
        int t = (threadIdx.x >= (unsigned)off) ? pref[threadIdx.x - off] : 0;
        __syncthreads();
        pref[threadIdx.x] += t;
        __syncthreads();
    }
    const int gb = (b == 0) ? 0 : pref[b - 1];
    const int span = pref[b] - gb;
    if (b == NBUCK - 1 && threadIdx.x == 0) row_start[NN] = NE;
    const unsigned* mybin = bin + (size_t)b * BIN_CAP;

    hist[threadIdx.x] = 0;
    __syncthreads();
    for (int i = threadIdx.x; i < span; i += 256)
        atomicAdd(&hist[mybin[i] >> 16], 1);
    __syncthreads();

    const int hv = hist[threadIdx.x];
    __syncthreads();
    hist[threadIdx.x] = hv;
    __syncthreads();
    for (int off = 1; off < 256; off <<= 1) {
        int tv = (threadIdx.x >= (unsigned)off) ? hist[threadIdx.x - off] : 0;
        __syncthreads();
        hist[threadIdx.x] += tv;
        __syncthreads();
    }
    const int ex = hist[threadIdx.x] - hv;
    __syncthreads();
    hist[threadIdx.x] = ex;
    if ((int)threadIdx.x < nn) row_start[nbase + threadIdx.x] = gb + ex;
    __syncthreads();

    for (int i = threadIdx.x; i < span; i += 256) {
        const unsigned u = mybin[i];
        const int pos = atomicAdd(&hist[u >> 16], 1);
        const unsigned short sv = (unsigned short)(u & 0xffffu);
        if (pos < SORT_WIN) win[pos] = sv;
        else src16[gb + pos] = sv;  // statistical overflow fallback
    }
    __syncthreads();
    const int lim = span < SORT_WIN ? span : SORT_WIN;
    for (int i = threadIdx.x; i < lim; i += 256) src16[gb + i] = win[i];
}

// ---- quad-split gather-mean: one wave per node, max TLP (do NOT fuse) ----
__device__ inline void acc8(float* s, uint4 r) {
    s[0] += bf2f(r.x & 0xffffu); s[1] += bf2f(r.x >> 16);
    s[2] += bf2f(r.y & 0xffffu); s[3] += bf2f(r.y >> 16);
    s[4] += bf2f(r.z & 0xffffu); s[5] += bf2f(r.z >> 16);
    s[6] += bf2f(r.w & 0xffffu); s[7] += bf2f(r.w >> 16);
}

__global__ __launch_bounds__(256)
void gather_mean4(const uint4* __restrict__ P4, const int* __restrict__ row_start,
                  const unsigned short* __restrict__ src16,
                  uint4* __restrict__ agg4) {
    const int n = blockIdx.x * 4 + (threadIdx.x >> 6);
    const int lane = threadIdx.x & 63;
    const int q = lane >> 4;
    const int l16 = lane & 15;
    const int b = row_start[n];
    const int e = row_start[n + 1];

    float s[8];
#pragma unroll
    for (int j = 0; j < 8; ++j) s[j] = 0.f;

    int i = b;
    for (; i + 32 <= e; i += 32) {
        int idx[8];
        uint4 r[8];
#pragma unroll
        for (int j = 0; j < 8; ++j) idx[j] = src16[i + j * 4 + q];
#pragma unroll
        for (int j = 0; j < 8; ++j) r[j] = P4[idx[j] * 16 + l16];
#pragma unroll
        for (int j = 0; j < 8; ++j) acc8(s, r[j]);
    }
    for (; i + 16 <= e; i += 16) {
        int i0 = src16[i + 0 + q], i1 = src16[i + 4 + q];
        int i2 = src16[i + 8 + q], i3 = src16[i + 12 + q];
        uint4 r0 = P4[i0 * 16 + l16];
        uint4 r1 = P4[i1 * 16 + l16];
        uint4 r2 = P4[i2 * 16 + l16];
        uint4 r3 = P4[i3 * 16 + l16];
        acc8(s, r0); acc8(s, r1); acc8(s, r2); acc8(s, r3);
    }
    for (; i + 4 <= e; i += 4) {
        int i0 = src16[i + q];
        uint4 r0 = P4[i0 * 16 + l16];
        acc8(s, r0);
    }
    const int rem = e - i;
    if (q < rem) {
        int i0 = src16[i + q];
        uint4 r0 = P4[i0 * 16 + l16];
        acc8(s, r0);
    }

#pragma unroll
    for (int j = 0; j < 8; ++j) {
        s[j] += __shfl_xor(s[j], 16);
        s[j] += __shfl_xor(s[j], 32);
    }

    const int deg = e - b;
    const float inv = 1.0f / (float)(deg > 0 ? deg : 1);
    if (q == 0) {
        uint4 o;
        o.x = (unsigned)f2bf(s[0] * inv) | ((unsigned)f2bf(s[1] * inv) << 16);
        o.y = (unsigned)f2bf(s[2] * inv) | ((unsigned)f2bf(s[3] * inv) << 16);
        o.z = (unsigned)f2bf(s[4] * inv) | ((unsigned)f2bf(s[5] * inv) << 16);
        o.w = (unsigned)f2bf(s[6] * inv) | ((unsigned)f2bf(s[7] * inv) << 16);
        agg4[n * 16 + l16] = o;
    }
}

extern "C" void kernel_launch(void* const* d_in, const int* in_sizes, int n_in,
                              void* d_out, int out_size, void* d_ws, size_t ws_size,
                              hipStream_t stream) {
    const float* x   = (const float*)d_in[0];
    const int*   ei  = (const int*)d_in[1];
    const float* Wp1 = (const float*)d_in[2];
    const float* bp1 = (const float*)d_in[3];
    const float* Wl1 = (const float*)d_in[4];
    const float* bl1 = (const float*)d_in[5];
    const float* Wr1 = (const float*)d_in[6];
    const float* Wp2 = (const float*)d_in[7];
    const float* bp2 = (const float*)d_in[8];
    const float* Wl2 = (const float*)d_in[9];
    const float* bl2 = (const float*)d_in[10];
    const float* Wr2 = (const float*)d_in[11];
    float* out = (float*)d_out;

    char* ws = (char*)d_ws;
    size_t off = 0;
    auto alloc = [&](size_t bytes) {
        void* p = ws + off;
        off += (bytes + 511) & ~511ull;
        return p;
    };
    unsigned short* Wb   = (unsigned short*)alloc((size_t)6 * D * D * 2);
    unsigned short* xb   = (unsigned short*)alloc((size_t)NN * D * 2);
    unsigned short* bufP = (unsigned short*)alloc((size_t)NN * D * 2);  // proj
    unsigned short* bufAg= (unsigned short*)alloc((size_t)NN * D * 2);  // agg
    unsigned short* bufH = (unsigned short*)alloc((size_t)NN * D * 2);  // layer-1 out
    unsigned short* bufP2= (unsigned short*)alloc((size_t)NN * D * 2);  // proj-2
    int* row_start  = (int*)alloc((size_t)(NN + 1) * 4);
    int* bcur       = (int*)alloc((size_t)NBUCK * 4);
    unsigned* bin   = (unsigned*)alloc((size_t)NBUCK * BIN_CAP * 4);
    unsigned short* src16 = (unsigned short*)alloc((size_t)NE * 2);

    // 1. conversions + edge binning (one dispatch)
    hipMemsetAsync(bcur, 0, (size_t)NBUCK * 4, stream);
    prep<<<XBLK + WBLK + BBLK, 256, 0, stream>>>(
        x, Wp1, Wl1, Wr1, Wp2, Wl2, Wr2, ei, xb, Wb, bin, bcur);

    // 2. bucket CSR sort (self-scanned, blocks first) + layer-1 projection gemm
    gemm_fill<<<NBUCK + GGRID, 256, 0, stream>>>(
        xb, Wb + 0 * D * D, bp1, bufP, bcur, bin, row_start, src16);

    const int GA = NN / 4;  // 12500 gather blocks

    // 3. layer-1 aggregate; combine1 fused with layer-2 projection
    gather_mean4<<<GA, 256, 0, stream>>>(
        (const uint4*)bufP, row_start, src16, (uint4*)bufAg);
    combine_proj<<<GGRID, 256, 0, stream>>>(
        bufAg, Wb + 1 * D * D, xb, Wb + 2 * D * D, bl1, bufH,
        Wb + 3 * D * D, bp2, bufP2);

    // 4. layer-2 aggregate + combine (f32 out)
    gather_mean4<<<GA, 256, 0, stream>>>(
        (const uint4*)bufP2, row_start, src16, (uint4*)bufAg);
    gemm_persist<float, true><<<GGRID, 256, 0, stream>>>(
        bufAg, Wb + 4 * D * D, bufH, Wb + 5 * D * D, bl2, out, 0);
}

// Round 14
// 245.675 us; speedup vs baseline: 1.1948x; 1.0709x over previous
//
#include <hip/hip_runtime.h>

#define NN 50000
#define NE 800000
#define D 128
#define NTILE 3128        // 16-row tiles: 3128*16 = 50048
#define GGRID 768         // persistent gemm blocks (3/CU — 1536 regressed, R13)
#define XBLK 6250         // x conversion blocks (NN*D/4/256)
#define WBLK 96           // weight conversion blocks (6 * 16)
#define BBLK 250          // edge-binning blocks
#define EPB 3200          // NE / BBLK edges per binning block
#define NBUCK 196         // dst>>8 buckets (256 nodes each)
#define STAGE_CAP 64      // LDS staging slots/bucket (mean 16.3, +12 sigma)
#define BIN_CAP 4608      // global bin capacity (mean 4096, +8 sigma)
#define SORT_WIN 4608     // LDS sort window entries
#define LDS_STRIDE 136    // tile row stride in ushorts (128 + 8 pad)

typedef __attribute__((ext_vector_type(8))) short bf16x8;
typedef __attribute__((ext_vector_type(4))) float f32x4;

__device__ inline unsigned short f2bf(float f) {
    union { float f; unsigned u; } v; v.f = f;
    unsigned r = v.u + 0x7FFF + ((v.u >> 16) & 1);  // RNE
    return (unsigned short)(r >> 16);
}
__device__ inline float bf2f(unsigned b) {
    union { unsigned u; float f; } v; v.u = b << 16;
    return v.f;
}

// ---- fused: convert x + 6 weights to bf16; bin edges to dst-buckets ----
__global__ __launch_bounds__(256)
void prep(const float* __restrict__ x,
          const float* __restrict__ w0, const float* __restrict__ w1,
          const float* __restrict__ w2, const float* __restrict__ w3,
          const float* __restrict__ w4, const float* __restrict__ w5,
          const int* __restrict__ ei,
          unsigned short* __restrict__ xb, unsigned short* __restrict__ wb,
          unsigned* __restrict__ bin, int* __restrict__ bcur) {
    const unsigned b = blockIdx.x;
    if (b < XBLK) {
        int i = b * 256 + threadIdx.x;
        float4 v = ((const float4*)x)[i];
        ushort4 o = {f2bf(v.x), f2bf(v.y), f2bf(v.z), f2bf(v.w)};
        ((ushort4*)xb)[i] = o;
    } else if (b < XBLK + WBLK) {
        const float* ws_[6] = {w0, w1, w2, w3, w4, w5};
        int wi = (int)(b - XBLK) >> 4;
        int off = ((int)(b - XBLK) & 15) * 256 + threadIdx.x;  // float4 idx
        float4 v = ((const float4*)ws_[wi])[off];
        ushort4 o = {f2bf(v.x), f2bf(v.y), f2bf(v.z), f2bf(v.w)};
        ((ushort4*)(wb + wi * D * D))[off] = o;
    } else {
        // bin 3200 edges: LDS-staged per-bucket appends, contiguous global spans.
        __shared__ unsigned stage[NBUCK * STAGE_CAP];
        __shared__ int bcnt[NBUCK];
        __shared__ int sbase[NBUCK];
        const int ebase = (int)(b - XBLK - WBLK) * EPB;
        if (threadIdx.x < NBUCK) bcnt[threadIdx.x] = 0;
        __syncthreads();
        for (int j = threadIdx.x; j < EPB; j += 256) {
            const int e = ebase + j;
            const int dst = ei[NE + e];
            const int src = ei[e];
            const int bk = dst >> 8;
            const unsigned u = (unsigned)src | ((unsigned)(dst & 255) << 16);
            const int slot = atomicAdd(&bcnt[bk], 1);
            if (slot < STAGE_CAP) {
                stage[bk * STAGE_CAP + slot] = u;
            } else {  // statistically-never overflow: direct append
                const int gp = atomicAdd(&bcur[bk], 1);
                if (gp < BIN_CAP) bin[bk * BIN_CAP + gp] = u;
            }
        }
        __syncthreads();
        if (threadIdx.x < NBUCK) {
            int c = bcnt[threadIdx.x];
            if (c > STAGE_CAP) c = STAGE_CAP;
            sbase[threadIdx.x] = atomicAdd(&bcur[threadIdx.x], c);
        }
        __syncthreads();
        const int wv = threadIdx.x >> 6, ln = threadIdx.x & 63;
        for (int bk = wv; bk < NBUCK; bk += 4) {
            int c = bcnt[bk];
            if (c > STAGE_CAP) c = STAGE_CAP;
            if (ln < c) {
                int p = sbase[bk] + ln;
                if (p < BIN_CAP) bin[bk * BIN_CAP + p] = stage[bk * STAGE_CAP + ln];
            }
        }
    }
}

// ---- persistent gemm body: out = A1@W1.T (+ A2@W2.T) + bias, opt relu ----
template <typename OUTT, bool DUAL>
__device__ inline void gemm_body(const unsigned short* __restrict__ A1,
                                 const unsigned short* __restrict__ W1,
                                 const unsigned short* __restrict__ A2,
                                 const unsigned short* __restrict__ W2,
                                 const float* __restrict__ bias,
                                 OUTT* __restrict__ out, int do_relu,
                                 int bid, int nblk) {
    const int lane = threadIdx.x & 63;
    const int wave = threadIdx.x >> 6;
    const int quad = lane >> 4;
    const int l16 = lane & 15;
    const int c0 = wave * 32 + l16;
    const int c1 = c0 + 16;

    const float bv0 = bias[c0];
    const float bv1 = bias[c1];

    bf16x8 w10[4], w11[4], w20[4], w21[4];
#pragma unroll
    for (int kt = 0; kt < 4; ++kt) {
        const int ko = kt * 32 + quad * 8;
        w10[kt] = *(const bf16x8*)&W1[c0 * D + ko];
        w11[kt] = *(const bf16x8*)&W1[c1 * D + ko];
        if (DUAL) {
            w20[kt] = *(const bf16x8*)&W2[c0 * D + ko];
            w21[kt] = *(const bf16x8*)&W2[c1 * D + ko];
        }
    }

    for (int t = bid; t < NTILE; t += nblk) {
        const int row0 = t * 16;
        int r = row0 + l16;
        const int arow = (r < NN ? r : NN - 1) * D;

        f32x4 acc0 = (f32x4){0.f, 0.f, 0.f, 0.f};
        f32x4 acc1 = (f32x4){0.f, 0.f, 0.f, 0.f};
#pragma unroll
        for (int kt = 0; kt < 4; ++kt) {
            const int ko = kt * 32 + quad * 8;
            bf16x8 a1 = *(const bf16x8*)&A1[arow + ko];
            acc0 = __builtin_amdgcn_mfma_f32_16x16x32_bf16(a1, w10[kt], acc0, 0, 0, 0);
            acc1 = __builtin_amdgcn_mfma_f32_16x16x32_bf16(a1, w11[kt], acc1, 0, 0, 0);
            if (DUAL) {
                bf16x8 a2 = *(const bf16x8*)&A2[arow + ko];
                acc0 = __builtin_amdgcn_mfma_f32_16x16x32_bf16(a2, w20[kt], acc0, 0, 0, 0);
                acc1 = __builtin_amdgcn_mfma_f32_16x16x32_bf16(a2, w21[kt], acc1, 0, 0, 0);
            }
        }

#pragma unroll
        for (int rr = 0; rr < 4; ++rr) {
            const int row = row0 + quad * 4 + rr;
            if (row < NN) {
                float v0 = acc0[rr] + bv0;
                float v1 = acc1[rr] + bv1;
                if (do_relu) {
                    v0 = v0 > 0.f ? v0 : 0.f;
                    v1 = v1 > 0.f ? v1 : 0.f;
                }
                if constexpr (sizeof(OUTT) == 2) {
                    out[row * D + c0] = (OUTT)f2bf(v0);
                    out[row * D + c1] = (OUTT)f2bf(v1);
                } else {
                    out[row * D + c0] = (OUTT)v0;
                    out[row * D + c1] = (OUTT)v1;
                }
            }
        }
    }
}

template <typename OUTT, bool DUAL>
__global__ __launch_bounds__(256)
void gemm_persist(const unsigned short* __restrict__ A1,
                  const unsigned short* __restrict__ W1,
                  const unsigned short* __restrict__ A2,
                  const unsigned short* __restrict__ W2,
                  const float* __restrict__ bias, OUTT* __restrict__ out,
                  int do_relu) {
    gemm_body<OUTT, DUAL>(A1, W1, A2, W2, bias, out, do_relu, blockIdx.x, GGRID);
}

// ---- fused: combine layer-1 + projection layer-2 (persistent tiles) ----
__global__ __launch_bounds__(256)
void combine_proj(const unsigned short* __restrict__ Ag,
                  const unsigned short* __restrict__ Wl,
                  const unsigned short* __restrict__ X,
                  const unsigned short* __restrict__ Wr,
                  const float* __restrict__ bl, unsigned short* __restrict__ bufH,
                  const unsigned short* __restrict__ Wp,
                  const float* __restrict__ bp, unsigned short* __restrict__ bufP2) {
    __shared__ unsigned short tile[16 * LDS_STRIDE];
    const int lane = threadIdx.x & 63;
    const int wave = threadIdx.x >> 6;
    const int quad = lane >> 4;
    const int l16 = lane & 15;
    const int c0 = wave * 32 + l16;
    const int c1 = c0 + 16;

    const float bl0 = bl[c0], bl1 = bl[c1];
    const float bp0 = bp[c0], bp1 = bp[c1];

    bf16x8 wl0[4], wl1[4], wr0[4], wr1[4];
#pragma unroll
    for (int kt = 0; kt < 4; ++kt) {
        const int ko = kt * 32 + quad * 8;
        wl0[kt] = *(const bf16x8*)&Wl[c0 * D + ko];
        wl1[kt] = *(const bf16x8*)&Wl[c1 * D + ko];
        wr0[kt] = *(const bf16x8*)&Wr[c0 * D + ko];
        wr1[kt] = *(const bf16x8*)&Wr[c1 * D + ko];
    }

    for (int t = blockIdx.x; t < NTILE; t += GGRID) {
        const int row0 = t * 16;
        int r = row0 + l16;
        const int arow = (r < NN ? r : NN - 1) * D;

        // phase A: dual combine
        f32x4 acc0 = (f32x4){0.f, 0.f, 0.f, 0.f};
        f32x4 acc1 = (f32x4){0.f, 0.f, 0.f, 0.f};
#pragma unroll
        for (int kt = 0; kt < 4; ++kt) {
            const int ko = kt * 32 + quad * 8;
            bf16x8 a1 = *(const bf16x8*)&Ag[arow + ko];
            bf16x8 a2 = *(const bf16x8*)&X[arow + ko];
            acc0 = __builtin_amdgcn_mfma_f32_16x16x32_bf16(a1, wl0[kt], acc0, 0, 0, 0);
            acc1 = __builtin_amdgcn_mfma_f32_16x16x32_bf16(a1, wl1[kt], acc1, 0, 0, 0);
            acc0 = __builtin_amdgcn_mfma_f32_16x16x32_bf16(a2, wr0[kt], acc0, 0, 0, 0);
            acc1 = __builtin_amdgcn_mfma_f32_16x16x32_bf16(a2, wr1[kt], acc1, 0, 0, 0);
        }
#pragma unroll
        for (int rr = 0; rr < 4; ++rr) {
            const int row = row0 + quad * 4 + rr;
            float v0 = acc0[rr] + bl0;
            float v1 = acc1[rr] + bl1;
            v0 = v0 > 0.f ? v0 : 0.f;
            v1 = v1 > 0.f ? v1 : 0.f;
            const unsigned short h0 = f2bf(v0), h1 = f2bf(v1);
            tile[(quad * 4 + rr) * LDS_STRIDE + c0] = h0;
            tile[(quad * 4 + rr) * LDS_STRIDE + c1] = h1;
            if (row < NN) {
                bufH[row * D + c0] = h0;
                bufH[row * D + c1] = h1;
            }
        }
        __syncthreads();

        // phase B: projection of the tile (A from LDS, Wp from L1/L2)
        f32x4 p0 = (f32x4){0.f, 0.f, 0.f, 0.f};
        f32x4 p1 = (f32x4){0.f, 0.f, 0.f, 0.f};
#pragma unroll
        for (int kt = 0; kt < 4; ++kt) {
            const int ko = kt * 32 + quad * 8;
            bf16x8 aL = *(const bf16x8*)&tile[l16 * LDS_STRIDE + ko];
            bf16x8 wp0 = *(const bf16x8*)&Wp[c0 * D + ko];
            bf16x8 wp1 = *(const bf16x8*)&Wp[c1 * D + ko];
            p0 = __builtin_amdgcn_mfma_f32_16x16x32_bf16(aL, wp0, p0, 0, 0, 0);
            p1 = __builtin_amdgcn_mfma_f32_16x16x32_bf16(aL, wp1, p1, 0, 0, 0);
        }
#pragma unroll
        for (int rr = 0; rr < 4; ++rr) {
            const int row = row0 + quad * 4 + rr;
            if (row < NN) {
                float v0 = p0[rr] + bp0;
                float v1 = p1[rr] + bp1;
                v0 = v0 > 0.f ? v0 : 0.f;
                v1 = v1 > 0.f ? v1 : 0.f;
                bufP2[row * D + c0] = f2bf(v0);
                bufP2[row * D + c1] = f2bf(v1);
            }
        }
        __syncthreads();  // protect LDS tile before next iteration
    }
}

// ---- fused: bucket CSR sort (blocks [0,NBUCK), critical path first) +
//      persistent layer-1 projection gemm. Sort blocks self-scan bcur[].
__global__ __launch_bounds__(256)
void gemm_fill(const unsigned short* __restrict__ A,
               const unsigned short* __restrict__ W,
               const float* __restrict__ bias, unsigned short* __restrict__ outp,
               const int* __restrict__ bcur, const unsigned* __restrict__ bin,
               int* __restrict__ row_start, unsigned short* __restrict__ src16) {
    if (blockIdx.x >= NBUCK) {
        gemm_body<unsigned short, false>(A, W, nullptr, nullptr, bias, outp, 1,
                                         (int)blockIdx.x - NBUCK, GGRID);
        return;
    }
    __shared__ int hist[256];
    __shared__ int pref[256];
    __shared__ unsigned short win[SORT_WIN];
    const int b = (int)blockIdx.x;  // 0..NBUCK-1
    const int nbase = b << 8;
    const int nn = (NN - nbase < 256) ? (NN - nbase) : 256;

    // self-scan of bucket counts -> gb (exclusive prefix), span
    int v = (threadIdx.x < NBUCK) ? bcur[threadIdx.x] : 0;
    pref[threadIdx.x] = v;
    __syncthreads();
    for (int off = 1; off < 256; off <<= 1) {
        int t = (threadIdx.x >= (unsigned)off) ? pref[threadIdx.x - off] : 0;
        __syncthreads();
        pref[threadIdx.x] += t;
        __syncthreads();
    }
    const int gb = (b == 0) ? 0 : pref[b - 1];
    const int span = pref[b] - gb;
    if (b == NBUCK - 1 && threadIdx.x == 0) row_start[NN] = NE;
    const unsigned* mybin = bin + (size_t)b * BIN_CAP;

    hist[threadIdx.x] = 0;
    __syncthreads();
    for (int i = threadIdx.x; i < span; i += 256)
        atomicAdd(&hist[mybin[i] >> 16], 1);
    __syncthreads();

    const int hv = hist[threadIdx.x];
    __syncthreads();
    hist[threadIdx.x] = hv;
    __syncthreads();
    for (int off = 1; off < 256; off <<= 1) {
        int tv = (threadIdx.x >= (unsigned)off) ? hist[threadIdx.x - off] : 0;
        __syncthreads();
        hist[threadIdx.x] += tv;
        __syncthreads();
    }
    const int ex = hist[threadIdx.x] - hv;
    __syncthreads();
    hist[threadIdx.x] = ex;
    if ((int)threadIdx.x < nn) row_start[nbase + threadIdx.x] = gb + ex;
    __syncthreads();

    for (int i = threadIdx.x; i < span; i += 256) {
        const unsigned u = mybin[i];
        const int pos = atomicAdd(&hist[u >> 16], 1);
        const unsigned short sv = (unsigned short)(u & 0xffffu);
        if (pos < SORT_WIN) win[pos] = sv;
        else src16[gb + pos] = sv;  // statistical overflow fallback
    }
    __syncthreads();
    const int lim = span < SORT_WIN ? span : SORT_WIN;
    for (int i = threadIdx.x; i < lim; i += 256) src16[gb + i] = win[i];
}

// ---- quad-split gather-mean: one wave per node, max TLP (do NOT fuse) ----
__device__ inline void acc8(float* s, uint4 r) {
    s[0] += bf2f(r.x & 0xffffu); s[1] += bf2f(r.x >> 16);
    s[2] += bf2f(r.y & 0xffffu); s[3] += bf2f(r.y >> 16);
    s[4] += bf2f(r.z & 0xffffu); s[5] += bf2f(r.z >> 16);
    s[6] += bf2f(r.w & 0xffffu); s[7] += bf2f(r.w >> 16);
}

__global__ __launch_bounds__(256)
void gather_mean4(const uint4* __restrict__ P4, const int* __restrict__ row_start,
                  const unsigned short* __restrict__ src16,
                  uint4* __restrict__ agg4) {
    const int n = blockIdx.x * 4 + (threadIdx.x >> 6);
    const int lane = threadIdx.x & 63;
    const int q = lane >> 4;
    const int l16 = lane & 15;
    const int b = row_start[n];
    const int e = row_start[n + 1];

    float s[8];
#pragma unroll
    for (int j = 0; j < 8; ++j) s[j] = 0.f;

    int i = b;
    for (; i + 32 <= e; i += 32) {
        int idx[8];
        uint4 r[8];
#pragma unroll
        for (int j = 0; j < 8; ++j) idx[j] = src16[i + j * 4 + q];
#pragma unroll
        for (int j = 0; j < 8; ++j) r[j] = P4[idx[j] * 16 + l16];
#pragma unroll
        for (int j = 0; j < 8; ++j) acc8(s, r[j]);
    }
    for (; i + 16 <= e; i += 16) {
        int i0 = src16[i + 0 + q], i1 = src16[i + 4 + q];
        int i2 = src16[i + 8 + q], i3 = src16[i + 12 + q];
        uint4 r0 = P4[i0 * 16 + l16];
        uint4 r1 = P4[i1 * 16 + l16];
        uint4 r2 = P4[i2 * 16 + l16];
        uint4 r3 = P4[i3 * 16 + l16];
        acc8(s, r0); acc8(s, r1); acc8(s, r2); acc8(s, r3);
    }
    for (; i + 4 <= e; i += 4) {
        int i0 = src16[i + q];
        uint4 r0 = P4[i0 * 16 + l16];
        acc8(s, r0);
    }
    const int rem = e - i;
    if (q < rem) {
        int i0 = src16[i + q];
        uint4 r0 = P4[i0 * 16 + l16];
        acc8(s, r0);
    }

#pragma unroll
    for (int j = 0; j < 8; ++j) {
        s[j] += __shfl_xor(s[j], 16);
        s[j] += __shfl_xor(s[j], 32);
    }

    const int deg = e - b;
    const float inv = 1.0f / (float)(deg > 0 ? deg : 1);
    if (q == 0) {
        uint4 o;
        o.x = (unsigned)f2bf(s[0] * inv) | ((unsigned)f2bf(s[1] * inv) << 16);
        o.y = (unsigned)f2bf(s[2] * inv) | ((unsigned)f2bf(s[3] * inv) << 16);
        o.z = (unsigned)f2bf(s[4] * inv) | ((unsigned)f2bf(s[5] * inv) << 16);
        o.w = (unsigned)f2bf(s[6] * inv) | ((unsigned)f2bf(s[7] * inv) << 16);
        agg4[n * 16 + l16] = o;
    }
}

extern "C" void kernel_launch(void* const* d_in, const int* in_sizes, int n_in,
                              void* d_out, int out_size, void* d_ws, size_t ws_size,
                              hipStream_t stream) {
    const float* x   = (const float*)d_in[0];
    const int*   ei  = (const int*)d_in[1];
    const float* Wp1 = (const float*)d_in[2];
    const float* bp1 = (const float*)d_in[3];
    const float* Wl1 = (const float*)d_in[4];
    const float* bl1 = (const float*)d_in[5];
    const float* Wr1 = (const float*)d_in[6];
    const float* Wp2 = (const float*)d_in[7];
    const float* bp2 = (const float*)d_in[8];
    const float* Wl2 = (const float*)d_in[9];
    const float* bl2 = (const float*)d_in[10];
    const float* Wr2 = (const float*)d_in[11];
    float* out = (float*)d_out;

    char* ws = (char*)d_ws;
    size_t off = 0;
    auto alloc = [&](size_t bytes) {
        void* p = ws + off;
        off += (bytes + 511) & ~511ull;
        return p;
    };
    unsigned short* Wb   = (unsigned short*)alloc((size_t)6 * D * D * 2);
    unsigned short* xb   = (unsigned short*)alloc((size_t)NN * D * 2);
    unsigned short* bufP = (unsigned short*)alloc((size_t)NN * D * 2);  // proj
    unsigned short* bufAg= (unsigned short*)alloc((size_t)NN * D * 2);  // agg
    unsigned short* bufH = (unsigned short*)alloc((size_t)NN * D * 2);  // layer-1 out
    unsigned short* bufP2= (unsigned short*)alloc((size_t)NN * D * 2);  // proj-2
    int* row_start  = (int*)alloc((size_t)(NN + 1) * 4);
    int* bcur       = (int*)alloc((size_t)NBUCK * 4);
    unsigned* bin   = (unsigned*)alloc((size_t)NBUCK * BIN_CAP * 4);
    unsigned short* src16 = (unsigned short*)alloc((size_t)NE * 2);

    // 1. conversions + edge binning (one dispatch)
    hipMemsetAsync(bcur, 0, (size_t)NBUCK * 4, stream);
    prep<<<XBLK + WBLK + BBLK, 256, 0, stream>>>(
        x, Wp1, Wl1, Wr1, Wp2, Wl2, Wr2, ei, xb, Wb, bin, bcur);

    // 2. bucket CSR sort (self-scanned, blocks first) + layer-1 projection gemm
    gemm_fill<<<NBUCK + GGRID, 256, 0, stream>>>(
        xb, Wb + 0 * D * D, bp1, bufP, bcur, bin, row_start, src16);

    const int GA = NN / 4;  // 12500 gather blocks

    // 3. layer-1 aggregate; combine1 fused with layer-2 projection
    gather_mean4<<<GA, 256, 0, stream>>>(
        (const uint4*)bufP, row_start, src16, (uint4*)bufAg);
    combine_proj<<<GGRID, 256, 0, stream>>>(
        bufAg, Wb + 1 * D * D, xb, Wb + 2 * D * D, bl1, bufH,
        Wb + 3 * D * D, bp2, bufP2);

    // 4. layer-2 aggregate + combine (f32 out)
    gather_mean4<<<GA, 256, 0, stream>>>(
        (const uint4*)bufP2, row_start, src16, (uint4*)bufAg);
    gemm_persist<float, true><<<GGRID, 256, 0, stream>>>(
        bufAg, Wb + 4 * D * D, bufH, Wb + 5 * D * D, bl2, out, 0);
}